// Round 1
// 581.736 us; speedup vs baseline: 1.1193x; 1.1193x over previous
//
#include <hip/hip_runtime.h>
#include <math.h>

#define Bn 8
#define Hh 96
#define Ww 96
#define NPIX 9216        // Hh*Ww
#define FCn 768
#define Rr 12
#define Pp 16
#define KSn 13
#define TOPKn 24
#define CAPc 1536        // candidate-list capacity (fast path); fallback if more

__device__ __forceinline__ float gelu_f(float x) {
  // exact gelu: 0.5*x*(1+erf(x/sqrt(2)))
  return 0.5f * x * (1.0f + erff(x * 0.70710678118654752440f));
}

// ---------------------------------------------------------------------------
// K1: 1x1 conv FC->R, channel-split 4 ways (partial sums) for load balance.
// blockIdx = pixblk*4 + s; block handles 256 pixels x 192 input channels.
// ---------------------------------------------------------------------------
__global__ __launch_bounds__(256) void k_conv1_part(
    const float* __restrict__ feat, const float* __restrict__ w1,
    float* __restrict__ partial) {
  __shared__ float w1s[192 * 12];  // transposed slice: w1s[c*12+r]
  int s = blockIdx.x & 3;
  int pixblk = blockIdx.x >> 2;
  int c0 = s * 192;
  for (int i = threadIdx.x; i < 192 * 12; i += 256) {
    int c = i / 12, r = i % 12;
    w1s[i] = w1[r * FCn + c0 + c];
  }
  __syncthreads();
  int pix = pixblk * 256 + threadIdx.x;  // 0..73727
  int b = pix / NPIX, hw = pix % NPIX;
  const float* fb = feat + (size_t)b * FCn * NPIX + (size_t)c0 * NPIX + hw;
  float acc[12];
#pragma unroll
  for (int r = 0; r < 12; r++) acc[r] = 0.f;
  for (int c = 0; c < 192; c += 8) {
    float f[8];
#pragma unroll
    for (int u = 0; u < 8; u++) f[u] = fb[(size_t)(c + u) * NPIX];
#pragma unroll
    for (int u = 0; u < 8; u++) {
#pragma unroll
      for (int r = 0; r < 12; r++)
        acc[r] = fmaf(f[u], w1s[(c + u) * 12 + r], acc[r]);
    }
  }
  float* outp = partial + (size_t)s * (Bn * Rr * NPIX) +
                (size_t)b * Rr * NPIX + hw;
#pragma unroll
  for (int r = 0; r < 12; r++) outp[(size_t)r * NPIX] = acc[r];
}

// ---------------------------------------------------------------------------
// K1b: combine 4 partials + bias, GELU -> t1
// ---------------------------------------------------------------------------
__global__ __launch_bounds__(256) void k_bias_gelu(
    const float* __restrict__ partial, const float* __restrict__ b1,
    float* __restrict__ t1) {
  int e = blockIdx.x * 256 + threadIdx.x;
  if (e >= Bn * Rr * NPIX) return;
  int r = (e / NPIX) % Rr;
  const size_t N = (size_t)Bn * Rr * NPIX;
  float v = ((partial[e] + partial[e + N]) + partial[e + 2 * N]) +
            partial[e + 3 * N] + b1[r];
  t1[e] = gelu_f(v);
}

// ---------------------------------------------------------------------------
// K2: 3x3 conv R->R pad1 + GELU -> proj ; occ_raw = mean |proj| ;
//     cs_raw = avgpool3(|carrier|) (count_include_pad -> /9)
// ---------------------------------------------------------------------------
__global__ __launch_bounds__(256) void k_conv2(
    const float* __restrict__ t1, const float* __restrict__ w2,
    const float* __restrict__ b2, const float* __restrict__ carrier,
    float* __restrict__ proj, float* __restrict__ occ_raw,
    float* __restrict__ cs_raw) {
  __shared__ float w2s[Rr * Rr * 9];
  __shared__ float b2s[Rr];
  for (int i = threadIdx.x; i < Rr * Rr * 9; i += 256) w2s[i] = w2[i];
  if (threadIdx.x < Rr) b2s[threadIdx.x] = b2[threadIdx.x];
  __syncthreads();
  int pix = blockIdx.x * 256 + threadIdx.x;
  int b = pix / NPIX, hw = pix % NPIX;
  int y = hw / Ww, x = hw % Ww;
  float acc[12];
#pragma unroll
  for (int r = 0; r < 12; r++) acc[r] = 0.f;
  const float* tb = t1 + (size_t)b * Rr * NPIX;
  for (int ri = 0; ri < Rr; ri++) {
    const float* tc = tb + (size_t)ri * NPIX;
#pragma unroll
    for (int ky = 0; ky < 3; ky++) {
      int yy = y + ky - 1;
      if (yy < 0 || yy >= Hh) continue;
#pragma unroll
      for (int kx = 0; kx < 3; kx++) {
        int xx = x + kx - 1;
        if (xx < 0 || xx >= Ww) continue;
        float v = tc[yy * Ww + xx];
#pragma unroll
        for (int ro = 0; ro < 12; ro++)
          acc[ro] = fmaf(v, w2s[((ro * Rr + ri) * 3 + ky) * 3 + kx], acc[ro]);
      }
    }
  }
  float asum = 0.f;
  float* pb = proj + (size_t)b * Rr * NPIX + hw;
#pragma unroll
  for (int ro = 0; ro < 12; ro++) {
    float g = gelu_f(acc[ro] + b2s[ro]);
    pb[(size_t)ro * NPIX] = g;
    asum += fabsf(g);
  }
  occ_raw[pix] = asum / 12.0f;

  const float* cb = carrier + (size_t)b * NPIX;
  float s9 = 0.f;
  for (int dy = -1; dy <= 1; dy++) {
    int yy = y + dy;
    if (yy < 0 || yy >= Hh) continue;
    for (int dx = -1; dx <= 1; dx++) {
      int xx = x + dx;
      if (xx < 0 || xx >= Ww) continue;
      s9 += fabsf(cb[yy * Ww + xx]);
    }
  }
  cs_raw[pix] = s9 / 9.0f;
}

// ---------------------------------------------------------------------------
// K3: per-image min/max of {occ_raw, cs_raw, density}. blockIdx = a*8+b.
// ---------------------------------------------------------------------------
__global__ __launch_bounds__(256) void k_minmax(
    const float* __restrict__ occ_raw, const float* __restrict__ cs_raw,
    const float* __restrict__ density, float* __restrict__ stats) {
  int a = blockIdx.x / Bn, b = blockIdx.x % Bn;
  const float* src = (a == 0) ? occ_raw : (a == 1) ? cs_raw : density;
  src += (size_t)b * NPIX;
  __shared__ float smn[256], smx[256];
  float mn = INFINITY, mx = -INFINITY;
  for (int p = threadIdx.x; p < NPIX; p += 256) {
    float v = src[p];
    mn = fminf(mn, v);
    mx = fmaxf(mx, v);
  }
  smn[threadIdx.x] = mn;
  smx[threadIdx.x] = mx;
  __syncthreads();
  for (int s = 128; s > 0; s >>= 1) {
    if (threadIdx.x < s) {
      smn[threadIdx.x] = fminf(smn[threadIdx.x], smn[threadIdx.x + s]);
      smx[threadIdx.x] = fmaxf(smx[threadIdx.x], smx[threadIdx.x + s]);
    }
    __syncthreads();
  }
  if (threadIdx.x == 0) {
    stats[(a * Bn + b) * 2 + 0] = smn[0];
    stats[(a * Bn + b) * 2 + 1] = smx[0];
  }
}

// ---------------------------------------------------------------------------
// K4: one block per image. normalize occ/cs/ds; ev threshold; erosion;
// dilation; dilation -> sup; scores = occ*sup. Masks live in LDS bytes.
// ---------------------------------------------------------------------------
__global__ __launch_bounds__(1024) void k_support(
    const float* __restrict__ occ_raw, const float* __restrict__ cs_raw,
    const float* __restrict__ density, const float* __restrict__ stats,
    float* __restrict__ occ, float* __restrict__ ds, float* __restrict__ sup,
    float* __restrict__ scores) {
  __shared__ unsigned char mA[NPIX], mB[NPIX];
  int b = blockIdx.x;
  float omn = stats[(0 * Bn + b) * 2], omx = stats[(0 * Bn + b) * 2 + 1];
  float cmn = stats[(1 * Bn + b) * 2], cmx = stats[(1 * Bn + b) * 2 + 1];
  float dmn = stats[(2 * Bn + b) * 2], dmx = stats[(2 * Bn + b) * 2 + 1];
  float oiv = fmaxf(omx - omn, 1e-6f);
  float civ = fmaxf(cmx - cmn, 1e-6f);
  float div_ = fmaxf(dmx - dmn, 1e-6f);
  float occ9[9];
#pragma unroll
  for (int i = 0; i < 9; i++) {
    int p = threadIdx.x + i * 1024;
    float oc = (occ_raw[b * NPIX + p] - omn) / oiv;
    float cv = (cs_raw[b * NPIX + p] - cmn) / civ;
    float dv = (density[b * NPIX + p] - dmn) / div_;
    occ[b * NPIX + p] = oc;
    ds[b * NPIX + p] = dv;
    occ9[i] = oc;
    float ev = 0.8f * cv + 0.2f * dv;
    mA[p] = (ev >= 0.28f) ? 1 : 0;
  }
  __syncthreads();
  // erosion: AND over in-bounds 3x3 (maxpool pads -inf -> only valid cells)
#pragma unroll
  for (int i = 0; i < 9; i++) {
    int p = threadIdx.x + i * 1024;
    int y = p / Ww, x = p % Ww;
    unsigned char m = 1;
    for (int dy = -1; dy <= 1; dy++) {
      int yy = y + dy;
      if (yy < 0 || yy >= Hh) continue;
      for (int dx = -1; dx <= 1; dx++) {
        int xx = x + dx;
        if (xx < 0 || xx >= Ww) continue;
        m = (unsigned char)(m & mA[yy * Ww + xx]);
      }
    }
    mB[p] = m;
  }
  __syncthreads();
  // dilation 1: OR over in-bounds 3x3
#pragma unroll
  for (int i = 0; i < 9; i++) {
    int p = threadIdx.x + i * 1024;
    int y = p / Ww, x = p % Ww;
    unsigned char m = 0;
    for (int dy = -1; dy <= 1; dy++) {
      int yy = y + dy;
      if (yy < 0 || yy >= Hh) continue;
      for (int dx = -1; dx <= 1; dx++) {
        int xx = x + dx;
        if (xx < 0 || xx >= Ww) continue;
        m = (unsigned char)(m | mB[yy * Ww + xx]);
      }
    }
    mA[p] = m;
  }
  __syncthreads();
  // dilation 2 (DIL=3): OR over in-bounds 3x3 -> sup; scores = occ*sup
#pragma unroll
  for (int i = 0; i < 9; i++) {
    int p = threadIdx.x + i * 1024;
    int y = p / Ww, x = p % Ww;
    unsigned char m = 0;
    for (int dy = -1; dy <= 1; dy++) {
      int yy = y + dy;
      if (yy < 0 || yy >= Hh) continue;
      for (int dx = -1; dx <= 1; dx++) {
        int xx = x + dx;
        if (xx < 0 || xx >= Ww) continue;
        m = (unsigned char)(m | mA[yy * Ww + xx]);
      }
    }
    float sv = (float)m;
    sup[b * NPIX + p] = sv;
    scores[b * NPIX + p] = occ9[i] * sv;
  }
}

// ---------------------------------------------------------------------------
// K5: NMS peak mask + top-24 via CANDIDATE COMPACTION.
// Peaks (score>=3x3 max, >0.05) are sparse (<= ~NPIX/9); compact (val,idx)
// into an LDS list, then 24 selection rounds over the short list using
// 64-lane shuffle butterflies (1 barrier/round instead of 8, ~36x less scan).
// Ties: value desc, pixel-index asc (== lax.top_k). When candidates run out,
// reference fills with val=0 entries whose idx cannot affect any output
// (foot*=val, anchor_map sets 0 on zero map) -> emit val=0, idx=0.
// Fallback (cnt > CAPc, e.g. giant equal plateau): full-LDS-scan selection.
// ---------------------------------------------------------------------------
__global__ __launch_bounds__(256) void k_topk(
    const float* __restrict__ scores, float* __restrict__ vals,
    int* __restrict__ idxs, float* __restrict__ anchor) {
  __shared__ float flat[NPIX];   // raw scores, then peak map (fallback path)
  __shared__ float cval[CAPc];
  __shared__ int cidx[CAPc];
  __shared__ int cnt;
  __shared__ float rv[4];
  __shared__ int ri[4], rs[4];
  int b = blockIdx.x;
  const int tid = threadIdx.x;
  const int lane = tid & 63, wid = tid >> 6;
  const float* sc = scores + (size_t)b * NPIX;
  // stage raw scores to LDS (coalesced, once)
#pragma unroll
  for (int i = 0; i < NPIX / 256; i++) flat[tid + i * 256] = sc[tid + i * 256];
  if (tid == 0) cnt = 0;
  __syncthreads();
  // NMS from LDS into registers
  float pk[NPIX / 256];
#pragma unroll
  for (int i = 0; i < NPIX / 256; i++) {
    int p = tid + i * 256;
    int y = p / Ww, x = p % Ww;
    float s = flat[p];
    float lm = -INFINITY;
    for (int dy = -1; dy <= 1; dy++) {
      int yy = y + dy;
      if (yy < 0 || yy >= Hh) continue;
      for (int dx = -1; dx <= 1; dx++) {
        int xx = x + dx;
        if (xx < 0 || xx >= Ww) continue;
        lm = fmaxf(lm, flat[yy * Ww + xx]);
      }
    }
    pk[i] = (s >= lm && s > 0.05f) ? s : 0.0f;
  }
  __syncthreads();
  // overwrite flat with peak map + compact positive candidates
#pragma unroll
  for (int i = 0; i < NPIX / 256; i++) {
    int p = tid + i * 256;
    flat[p] = pk[i];
    if (pk[i] > 0.f) {
      int slot = atomicAdd(&cnt, 1);
      if (slot < CAPc) {
        cval[slot] = pk[i];
        cidx[slot] = p;
      }
    }
  }
  __syncthreads();
  const int C = cnt;
  if (C <= CAPc) {
    // ---- fast path: iterate over the compacted candidate list ----
    for (int k = 0; k < TOPKn; k++) {
      float bv = -INFINITY;
      int bi = 0x7fffffff, bs = -1;
      for (int j = tid; j < C; j += 256) {
        float v = cval[j];
        int pi = cidx[j];
        if (v > bv || (v == bv && pi < bi)) {
          bv = v;
          bi = pi;
          bs = j;
        }
      }
      // 64-lane butterfly (lexicographic max is associative+commutative)
      for (int off = 32; off > 0; off >>= 1) {
        float ov = __shfl_xor(bv, off);
        int oi = __shfl_xor(bi, off);
        int os = __shfl_xor(bs, off);
        if (ov > bv || (ov == bv && oi < bi)) {
          bv = ov;
          bi = oi;
          bs = os;
        }
      }
      if (lane == 0) {
        rv[wid] = bv;
        ri[wid] = bi;
        rs[wid] = bs;
      }
      __syncthreads();
      if (tid == 0) {
        float Bv = rv[0];
        int Bi = ri[0], Bs = rs[0];
        for (int w = 1; w < 4; w++) {
          if (rv[w] > Bv || (rv[w] == Bv && ri[w] < Bi)) {
            Bv = rv[w];
            Bi = ri[w];
            Bs = rs[w];
          }
        }
        if (Bv > 0.f) {
          vals[b * TOPKn + k] = Bv;
          idxs[b * TOPKn + k] = Bi;
          anchor[b * NPIX + Bi] = Bv;
          cval[Bs] = -INFINITY;  // consume
        } else {
          vals[b * TOPKn + k] = 0.f;
          idxs[b * TOPKn + k] = 0;  // idx irrelevant when val==0
        }
      }
      __syncthreads();
    }
  } else {
    // ---- fallback: full scan over peak map in LDS ----
    for (int k = 0; k < TOPKn; k++) {
      float bv = -INFINITY;
      int bi = 0x7fffffff;
      for (int p = tid; p < NPIX; p += 256) {
        float v = flat[p];
        if (v > bv || (v == bv && p < bi)) {
          bv = v;
          bi = p;
        }
      }
      for (int off = 32; off > 0; off >>= 1) {
        float ov = __shfl_xor(bv, off);
        int oi = __shfl_xor(bi, off);
        if (ov > bv || (ov == bv && oi < bi)) {
          bv = ov;
          bi = oi;
        }
      }
      if (lane == 0) {
        rv[wid] = bv;
        ri[wid] = bi;
      }
      __syncthreads();
      if (tid == 0) {
        float Bv = rv[0];
        int Bi = ri[0];
        for (int w = 1; w < 4; w++) {
          if (rv[w] > Bv || (rv[w] == Bv && ri[w] < Bi)) {
            Bv = rv[w];
            Bi = ri[w];
          }
        }
        if (Bv > 0.f) {
          vals[b * TOPKn + k] = Bv;
          idxs[b * TOPKn + k] = Bi;
          anchor[b * NPIX + Bi] = Bv;
          flat[Bi] = -INFINITY;  // consume
        } else {
          vals[b * TOPKn + k] = 0.f;
          idxs[b * TOPKn + k] = 0;
        }
      }
      __syncthreads();
    }
  }
}

// ---------------------------------------------------------------------------
// K6: per-anchor prototype argmax + oriented Gaussian stamp (atomicAdd).
// One block per (b,k). 192 threads; threads 0..168 cover 13x13 cells.
// ---------------------------------------------------------------------------
__global__ __launch_bounds__(192) void k_stamp(
    const float* __restrict__ proj, const float* __restrict__ proto,
    const float* __restrict__ vals, const int* __restrict__ idxs,
    float* __restrict__ canvas) {
  int b = blockIdx.x / TOPKn, k = blockIdx.x % TOPKn;
  __shared__ float embs[12];
  __shared__ float prm[5];  // cos, sin, len, wid, val
  __shared__ int ppos[2];   // ys, xs
  if (threadIdx.x == 0) {
    int id = idxs[b * TOPKn + k];
    float v = vals[b * TOPKn + k];
    float ft[12];
    for (int r = 0; r < 12; r++)
      ft[r] = proj[(size_t)(b * Rr + r) * NPIX + id];
    float bestL = -INFINITY;
    int bp = 0;
    for (int p = 0; p < Pp; p++) {
      float L = 0.f;
      for (int r = 0; r < 12; r++) L = fmaf(ft[r], proto[p * Rr + r], L);
      if (L > bestL) {  // strict: first occurrence wins (matches argmax)
        bestL = L;
        bp = p;
      }
    }
    const float lenL[4] = {0.4f, 0.7f, 1.0f, 1.25f};
    const float widL[4] = {0.12f, 0.18f, 0.24f, 0.3f};
    float ori = (float)((M_PI / 16.0) * (double)bp);  // linspace(0,pi,17)[:16]
    prm[0] = cosf(ori);
    prm[1] = sinf(ori);
    prm[2] = lenL[bp & 3];
    prm[3] = widL[(bp >> 2) & 3];
    prm[4] = v;
    ppos[0] = id / Ww;
    ppos[1] = id % Ww;
    for (int r = 0; r < 12; r++) embs[r] = proto[bp * Rr + r];
  }
  __syncthreads();
  float v = prm[4];
  if (v <= 0.f) return;  // zero-valued anchors contribute nothing
  int t = threadIdx.x;
  if (t >= KSn * KSn) return;
  int i = t / KSn, j = t % KSn;
  float gx = (float)(-1.0 + (double)j * (1.0 / 6.0));  // linspace(-1,1,13)
  float gy = (float)(-1.0 + (double)i * (1.0 / 6.0));
  float c = prm[0], s = prm[1];
  float xr = c * gx + s * gy;
  float yr = -s * gx + c * gy;
  float tx = xr / prm[2], ty = yr / prm[3];
  float foot = expf(-(tx * tx) - (ty * ty)) * v;
  int yy = ppos[0] + i - KSn / 2;
  int xx = ppos[1] + j - KSn / 2;
  if (yy < 0 || yy >= Hh || xx < 0 || xx >= Ww) return;
  float* cp = canvas + (size_t)b * Rr * NPIX + yy * Ww + xx;
#pragma unroll
  for (int r = 0; r < 12; r++) atomicAdd(cp + (size_t)r * NPIX, embs[r] * foot);
}

// ---------------------------------------------------------------------------
// K7: 1x1 conv 16->12 + GELU -> h.  in16 = [canvas*sup, occ, sup, anchor, ds]
// ---------------------------------------------------------------------------
__global__ __launch_bounds__(256) void k_post1(
    const float* __restrict__ canvas, const float* __restrict__ sup,
    const float* __restrict__ occ, const float* __restrict__ anchor,
    const float* __restrict__ ds, const float* __restrict__ w3,
    const float* __restrict__ b3, float* __restrict__ h) {
  __shared__ float w3s[12 * 16], b3s[12];
  for (int i = threadIdx.x; i < 192; i += 256) w3s[i] = w3[i];
  if (threadIdx.x < 12) b3s[threadIdx.x] = b3[threadIdx.x];
  __syncthreads();
  int pix = blockIdx.x * 256 + threadIdx.x;
  int b = pix / NPIX, hw = pix % NPIX;
  float in16[16];
  float sv = sup[pix];
#pragma unroll
  for (int r = 0; r < 12; r++)
    in16[r] = canvas[(size_t)(b * Rr + r) * NPIX + hw] * sv;
  in16[12] = occ[pix];
  in16[13] = sv;
  in16[14] = anchor[pix];
  in16[15] = ds[pix];
  float* hb = h + (size_t)b * Rr * NPIX + hw;
#pragma unroll
  for (int ro = 0; ro < 12; ro++) {
    float acc = 0.f;
#pragma unroll
    for (int ci = 0; ci < 16; ci++)
      acc = fmaf(in16[ci], w3s[ro * 16 + ci], acc);
    hb[(size_t)ro * NPIX] = gelu_f(acc + b3s[ro]);
  }
}

// ---------------------------------------------------------------------------
// K8: 1x1 conv 12->768 -> out. block = (b, ocgroup of 16, hw chunk of 256).
// w4 slice in LDS; h in registers; 16 coalesced stores per thread.
// ---------------------------------------------------------------------------
__global__ __launch_bounds__(256) void k_post2(
    const float* __restrict__ h, const float* __restrict__ w4,
    const float* __restrict__ b4, float* __restrict__ out) {
  __shared__ float w4s[16 * 12], b4s[16];
  int bx = blockIdx.x;
  int hwblk = bx % 36;
  int g = (bx / 36) % 48;
  int b = bx / (36 * 48);
  int oc0 = g * 16;
  for (int i = threadIdx.x; i < 192; i += 256) w4s[i] = w4[oc0 * 12 + i];
  if (threadIdx.x < 16) b4s[threadIdx.x] = b4[oc0 + threadIdx.x];
  __syncthreads();
  int hw = hwblk * 256 + threadIdx.x;
  float hreg[12];
  const float* hb = h + (size_t)b * Rr * NPIX + hw;
#pragma unroll
  for (int r = 0; r < 12; r++) hreg[r] = hb[(size_t)r * NPIX];
  float* ob = out + (size_t)(b * FCn + oc0) * NPIX + hw;
#pragma unroll
  for (int j = 0; j < 16; j++) {
    float acc = 0.f;
#pragma unroll
    for (int r = 0; r < 12; r++) acc = fmaf(hreg[r], w4s[j * 12 + r], acc);
    ob[(size_t)j * NPIX] = acc + b4s[j];
  }
}

// ---------------------------------------------------------------------------
extern "C" void kernel_launch(void* const* d_in, const int* in_sizes, int n_in,
                              void* d_out, int out_size, void* d_ws,
                              size_t ws_size, hipStream_t stream) {
  const float* features = (const float*)d_in[0];
  const float* carrier = (const float*)d_in[1];
  const float* density = (const float*)d_in[2];
  const float* w1 = (const float*)d_in[3];
  const float* b1 = (const float*)d_in[4];
  const float* w2 = (const float*)d_in[5];
  const float* b2 = (const float*)d_in[6];
  const float* w3 = (const float*)d_in[7];
  const float* b3 = (const float*)d_in[8];
  const float* w4 = (const float*)d_in[9];
  const float* b4 = (const float*)d_in[10];
  const float* proto = (const float*)d_in[11];
  float* out = (float*)d_out;
  float* ws = (float*)d_ws;

  const size_t NT = (size_t)Bn * Rr * NPIX;  // 884736
  float* t1 = ws;                            // [NT]
  float* partial = ws + NT;                  // [4*NT] (dead after k_bias_gelu)
  float* proj = partial;                     // reuse partial0
  float* canvas = partial + NT;              // reuse partial1
  float* h = partial + 2 * NT;               // reuse partial2
  float* sm = ws + 5 * NT;
  float* occ_raw = sm;                       // [8*NPIX]
  float* cs_raw = sm + (size_t)Bn * NPIX;
  float* occ = sm + 2 * (size_t)Bn * NPIX;
  float* ds = sm + 3 * (size_t)Bn * NPIX;
  float* sup = sm + 4 * (size_t)Bn * NPIX;
  float* scores = sm + 5 * (size_t)Bn * NPIX;
  float* anchor = sm + 6 * (size_t)Bn * NPIX;
  float* stats = sm + 7 * (size_t)Bn * NPIX;  // 48 floats
  float* vals = stats + 64;                   // 192 floats
  int* idxs = (int*)(vals + Bn * TOPKn);      // 192 ints

  // 1) 1x1 conv (channel-split partials)
  k_conv1_part<<<288 * 4, 256, 0, stream>>>(features, w1, partial);
  // 2) combine + bias + gelu -> t1
  k_bias_gelu<<<(int)((NT + 255) / 256), 256, 0, stream>>>(partial, b1, t1);
  // zero canvas + anchor (after partials are consumed; canvas aliases partial1)
  hipMemsetAsync(canvas, 0, NT * sizeof(float), stream);
  hipMemsetAsync(anchor, 0, (size_t)Bn * NPIX * sizeof(float), stream);
  // 3) 3x3 conv + gelu -> proj ; occ_raw ; cs_raw
  k_conv2<<<288, 256, 0, stream>>>(t1, w2, b2, carrier, proj, occ_raw, cs_raw);
  // 4) per-image min/max
  k_minmax<<<24, 256, 0, stream>>>(occ_raw, cs_raw, density, stats);
  // 5) support mask morphology + occ/ds/scores
  k_support<<<Bn, 1024, 0, stream>>>(occ_raw, cs_raw, density, stats, occ, ds,
                                     sup, scores);
  // 6) NMS + top-24 + anchor map (candidate-compacted)
  k_topk<<<Bn, 256, 0, stream>>>(scores, vals, idxs, anchor);
  // 7) prototype select + Gaussian stamp
  k_stamp<<<Bn * TOPKn, 192, 0, stream>>>(proj, proto, vals, idxs, canvas);
  // 8) 16->12 conv + gelu
  k_post1<<<288, 256, 0, stream>>>(canvas, sup, occ, anchor, ds, w3, b3, h);
  // 9) 12->768 conv -> out
  k_post2<<<Bn * 48 * 36, 256, 0, stream>>>(h, w4, b4, out);
}

// Round 3
// 562.421 us; speedup vs baseline: 1.1577x; 1.0343x over previous
//
#include <hip/hip_runtime.h>
#include <math.h>

#define Bn 8
#define Hh 96
#define Ww 96
#define NPIX 9216        // Hh*Ww
#define FCn 768
#define Rr 12
#define Pp 16
#define KSn 13
#define TOPKn 24
#define CAPc 1536        // candidate-list capacity (fast path); fallback if more

__device__ __forceinline__ float gelu_f(float x) {
  // exact gelu: 0.5*x*(1+erf(x/sqrt(2)))
  return 0.5f * x * (1.0f + erff(x * 0.70710678118654752440f));
}

// ---------------------------------------------------------------------------
// K1: 1x1 conv FC->R, channel-split 4 ways (partial sums).
// 2 px/thread, float2 loads (8B/lane). blockIdx = pixblk*4 + s.
// Block: 256 threads x 2 px = 512 px, 192 input channels.
// ---------------------------------------------------------------------------
__global__ __launch_bounds__(256) void k_conv1_part(
    const float* __restrict__ feat, const float* __restrict__ w1,
    float* __restrict__ partial) {
  __shared__ float w1s[192 * 12];  // transposed slice: w1s[c*12+r]
  int s = blockIdx.x & 3;
  int pixblk = blockIdx.x >> 2;  // 0..143
  int c0 = s * 192;
  for (int i = threadIdx.x; i < 192 * 12; i += 256) {
    int c = i / 12, r = i % 12;
    w1s[i] = w1[r * FCn + c0 + c];
  }
  __syncthreads();
  int px0 = pixblk * 512 + threadIdx.x * 2;  // 512 | 9216 -> no image straddle
  int b = px0 / NPIX, hw = px0 % NPIX;
  const float* fb = feat + (size_t)b * FCn * NPIX + (size_t)c0 * NPIX + hw;
  float acc0[12], acc1[12];
#pragma unroll
  for (int r = 0; r < 12; r++) { acc0[r] = 0.f; acc1[r] = 0.f; }
  for (int c = 0; c < 192; c += 4) {
    float2 f[4];
#pragma unroll
    for (int u = 0; u < 4; u++)
      f[u] = *(const float2*)(fb + (size_t)(c + u) * NPIX);
#pragma unroll
    for (int u = 0; u < 4; u++) {
#pragma unroll
      for (int r = 0; r < 12; r++) {
        float w = w1s[(c + u) * 12 + r];
        acc0[r] = fmaf(f[u].x, w, acc0[r]);
        acc1[r] = fmaf(f[u].y, w, acc1[r]);
      }
    }
  }
  float* outp = partial + (size_t)s * (Bn * Rr * NPIX) +
                (size_t)b * Rr * NPIX + hw;
#pragma unroll
  for (int r = 0; r < 12; r++)
    *(float2*)(outp + (size_t)r * NPIX) = make_float2(acc0[r], acc1[r]);
}

// ---------------------------------------------------------------------------
// K1b: combine 4 partials + bias, GELU -> t1 (float4). Also inits stats
// min/max slots (consumed by k_conv2's atomics).
// ---------------------------------------------------------------------------
__global__ __launch_bounds__(256) void k_bias_gelu(
    const float* __restrict__ partial, const float* __restrict__ b1,
    float* __restrict__ t1, unsigned int* __restrict__ statsu) {
  int e4 = blockIdx.x * 256 + threadIdx.x;  // 0..221183 (NT/4)
  const int Q = (Bn * Rr * NPIX) / 4;
  const float4* pp = (const float4*)partial;
  float4 a = pp[e4], b_ = pp[e4 + Q], c = pp[e4 + 2 * Q], d = pp[e4 + 3 * Q];
  int r = (e4 / (NPIX / 4)) % Rr;  // 4 consecutive elems share r (NPIX%4==0)
  float bias = b1[r];
  float4 v;
  v.x = gelu_f(((a.x + b_.x) + c.x) + d.x + bias);
  v.y = gelu_f(((a.y + b_.y) + c.y) + d.y + bias);
  v.z = gelu_f(((a.z + b_.z) + c.z) + d.z + bias);
  v.w = gelu_f(((a.w + b_.w) + c.w) + d.w + bias);
  ((float4*)t1)[e4] = v;
  if (e4 < 24) {  // 3 maps x 8 images; all maps are >= 0 -> uint-monotone
    statsu[e4 * 2 + 0] = 0x7f800000u;  // +inf (min slot)
    statsu[e4 * 2 + 1] = 0u;           // 0.0f (max slot; data >= 0)
  }
}

// ---------------------------------------------------------------------------
// K2: 3x3 conv R->R pad1 + GELU -> proj ; occ_raw = mean |proj| ;
//     cs_raw = avgpool3(|carrier|)/9 ; fused per-image min/max of
//     {occ_raw, cs_raw, density} via wave-reduce + uint atomics (exact for
//     non-negative floats). Also zeroes canvas (aliases partial1, dead now)
//     and anchor — replaces the 2 hipMemsetAsync + k_minmax dispatches.
// ---------------------------------------------------------------------------
__global__ __launch_bounds__(256) void k_conv2(
    const float* __restrict__ t1, const float* __restrict__ w2,
    const float* __restrict__ b2, const float* __restrict__ carrier,
    const float* __restrict__ density, float* __restrict__ proj,
    float* __restrict__ occ_raw, float* __restrict__ cs_raw,
    unsigned int* __restrict__ statsu, float* __restrict__ canvas,
    float* __restrict__ anchor) {
  __shared__ float w2s[Rr * Rr * 9];
  __shared__ float b2s[Rr];
  for (int i = threadIdx.x; i < Rr * Rr * 9; i += 256) w2s[i] = w2[i];
  if (threadIdx.x < Rr) b2s[threadIdx.x] = b2[threadIdx.x];
  int pix = blockIdx.x * 256 + threadIdx.x;  // exactly Bn*NPIX threads
  // zero canvas (NT floats = 3*Bn*NPIX float4s, coalesced) + anchor
  {
    float4 z = make_float4(0.f, 0.f, 0.f, 0.f);
    float4* c4 = (float4*)canvas;
#pragma unroll
    for (int q = 0; q < 3; q++) c4[(size_t)q * (Bn * NPIX) + pix] = z;
    anchor[pix] = 0.f;
  }
  __syncthreads();
  int b = pix / NPIX, hw = pix % NPIX;
  int y = hw / Ww, x = hw % Ww;
  float acc[12];
#pragma unroll
  for (int r = 0; r < 12; r++) acc[r] = 0.f;
  const float* tb = t1 + (size_t)b * Rr * NPIX;
  for (int ri = 0; ri < Rr; ri++) {
    const float* tc = tb + (size_t)ri * NPIX;
#pragma unroll
    for (int ky = 0; ky < 3; ky++) {
      int yy = y + ky - 1;
      if (yy < 0 || yy >= Hh) continue;
#pragma unroll
      for (int kx = 0; kx < 3; kx++) {
        int xx = x + kx - 1;
        if (xx < 0 || xx >= Ww) continue;
        float v = tc[yy * Ww + xx];
#pragma unroll
        for (int ro = 0; ro < 12; ro++)
          acc[ro] = fmaf(v, w2s[((ro * Rr + ri) * 3 + ky) * 3 + kx], acc[ro]);
      }
    }
  }
  float asum = 0.f;
  float* pb = proj + (size_t)b * Rr * NPIX + hw;
#pragma unroll
  for (int ro = 0; ro < 12; ro++) {
    float g = gelu_f(acc[ro] + b2s[ro]);
    pb[(size_t)ro * NPIX] = g;
    asum += fabsf(g);
  }
  float occv = asum / 12.0f;
  occ_raw[pix] = occv;

  const float* cb = carrier + (size_t)b * NPIX;
  float s9 = 0.f;
  for (int dy = -1; dy <= 1; dy++) {
    int yy = y + dy;
    if (yy < 0 || yy >= Hh) continue;
    for (int dx = -1; dx <= 1; dx++) {
      int xx = x + dx;
      if (xx < 0 || xx >= Ww) continue;
      s9 += fabsf(cb[yy * Ww + xx]);
    }
  }
  float csv = s9 / 9.0f;
  cs_raw[pix] = csv;
  float dv = density[pix];

  // wave-level min/max reduce (64 lanes), then per-wave uint atomics
  float mn0 = occv, mx0 = occv, mn1 = csv, mx1 = csv, mn2 = dv, mx2 = dv;
#pragma unroll
  for (int off = 32; off > 0; off >>= 1) {
    mn0 = fminf(mn0, __shfl_xor(mn0, off));
    mx0 = fmaxf(mx0, __shfl_xor(mx0, off));
    mn1 = fminf(mn1, __shfl_xor(mn1, off));
    mx1 = fmaxf(mx1, __shfl_xor(mx1, off));
    mn2 = fminf(mn2, __shfl_xor(mn2, off));
    mx2 = fmaxf(mx2, __shfl_xor(mx2, off));
  }
  if ((threadIdx.x & 63) == 0) {
    atomicMin(&statsu[(0 * Bn + b) * 2 + 0], __float_as_uint(mn0));
    atomicMax(&statsu[(0 * Bn + b) * 2 + 1], __float_as_uint(mx0));
    atomicMin(&statsu[(1 * Bn + b) * 2 + 0], __float_as_uint(mn1));
    atomicMax(&statsu[(1 * Bn + b) * 2 + 1], __float_as_uint(mx1));
    atomicMin(&statsu[(2 * Bn + b) * 2 + 0], __float_as_uint(mn2));
    atomicMax(&statsu[(2 * Bn + b) * 2 + 1], __float_as_uint(mx2));
  }
}

// ---------------------------------------------------------------------------
// K4: one block per image. normalize occ/cs/ds; ev threshold; erosion;
// dilation; dilation -> sup; scores = occ*sup. Masks live in LDS bytes.
// ---------------------------------------------------------------------------
__global__ __launch_bounds__(1024) void k_support(
    const float* __restrict__ occ_raw, const float* __restrict__ cs_raw,
    const float* __restrict__ density, const float* __restrict__ stats,
    float* __restrict__ occ, float* __restrict__ ds, float* __restrict__ sup,
    float* __restrict__ scores) {
  __shared__ unsigned char mA[NPIX], mB[NPIX];
  int b = blockIdx.x;
  float omn = stats[(0 * Bn + b) * 2], omx = stats[(0 * Bn + b) * 2 + 1];
  float cmn = stats[(1 * Bn + b) * 2], cmx = stats[(1 * Bn + b) * 2 + 1];
  float dmn = stats[(2 * Bn + b) * 2], dmx = stats[(2 * Bn + b) * 2 + 1];
  float oiv = fmaxf(omx - omn, 1e-6f);
  float civ = fmaxf(cmx - cmn, 1e-6f);
  float div_ = fmaxf(dmx - dmn, 1e-6f);
  float occ9[9];
#pragma unroll
  for (int i = 0; i < 9; i++) {
    int p = threadIdx.x + i * 1024;
    float oc = (occ_raw[b * NPIX + p] - omn) / oiv;
    float cv = (cs_raw[b * NPIX + p] - cmn) / civ;
    float dv = (density[b * NPIX + p] - dmn) / div_;
    occ[b * NPIX + p] = oc;
    ds[b * NPIX + p] = dv;
    occ9[i] = oc;
    float ev = 0.8f * cv + 0.2f * dv;
    mA[p] = (ev >= 0.28f) ? 1 : 0;
  }
  __syncthreads();
  // erosion: AND over in-bounds 3x3 (maxpool pads -inf -> only valid cells)
#pragma unroll
  for (int i = 0; i < 9; i++) {
    int p = threadIdx.x + i * 1024;
    int y = p / Ww, x = p % Ww;
    unsigned char m = 1;
    for (int dy = -1; dy <= 1; dy++) {
      int yy = y + dy;
      if (yy < 0 || yy >= Hh) continue;
      for (int dx = -1; dx <= 1; dx++) {
        int xx = x + dx;
        if (xx < 0 || xx >= Ww) continue;
        m = (unsigned char)(m & mA[yy * Ww + xx]);
      }
    }
    mB[p] = m;
  }
  __syncthreads();
  // dilation 1: OR over in-bounds 3x3
#pragma unroll
  for (int i = 0; i < 9; i++) {
    int p = threadIdx.x + i * 1024;
    int y = p / Ww, x = p % Ww;
    unsigned char m = 0;
    for (int dy = -1; dy <= 1; dy++) {
      int yy = y + dy;
      if (yy < 0 || yy >= Hh) continue;
      for (int dx = -1; dx <= 1; dx++) {
        int xx = x + dx;
        if (xx < 0 || xx >= Ww) continue;
        m = (unsigned char)(m | mB[yy * Ww + xx]);
      }
    }
    mA[p] = m;
  }
  __syncthreads();
  // dilation 2 (DIL=3): OR over in-bounds 3x3 -> sup; scores = occ*sup
#pragma unroll
  for (int i = 0; i < 9; i++) {
    int p = threadIdx.x + i * 1024;
    int y = p / Ww, x = p % Ww;
    unsigned char m = 0;
    for (int dy = -1; dy <= 1; dy++) {
      int yy = y + dy;
      if (yy < 0 || yy >= Hh) continue;
      for (int dx = -1; dx <= 1; dx++) {
        int xx = x + dx;
        if (xx < 0 || xx >= Ww) continue;
        m = (unsigned char)(m | mA[yy * Ww + xx]);
      }
    }
    float sv = (float)m;
    sup[b * NPIX + p] = sv;
    scores[b * NPIX + p] = occ9[i] * sv;
  }
}

// ---------------------------------------------------------------------------
// K5: NMS peak mask + top-24 via CANDIDATE COMPACTION (see round-0 notes).
// ---------------------------------------------------------------------------
__global__ __launch_bounds__(256) void k_topk(
    const float* __restrict__ scores, float* __restrict__ vals,
    int* __restrict__ idxs, float* __restrict__ anchor) {
  __shared__ float flat[NPIX];   // raw scores, then peak map (fallback path)
  __shared__ float cval[CAPc];
  __shared__ int cidx[CAPc];
  __shared__ int cnt;
  __shared__ float rv[4];
  __shared__ int ri[4], rs[4];
  int b = blockIdx.x;
  const int tid = threadIdx.x;
  const int lane = tid & 63, wid = tid >> 6;
  const float* sc = scores + (size_t)b * NPIX;
#pragma unroll
  for (int i = 0; i < NPIX / 256; i++) flat[tid + i * 256] = sc[tid + i * 256];
  if (tid == 0) cnt = 0;
  __syncthreads();
  float pk[NPIX / 256];
#pragma unroll
  for (int i = 0; i < NPIX / 256; i++) {
    int p = tid + i * 256;
    int y = p / Ww, x = p % Ww;
    float s = flat[p];
    float lm = -INFINITY;
    for (int dy = -1; dy <= 1; dy++) {
      int yy = y + dy;
      if (yy < 0 || yy >= Hh) continue;
      for (int dx = -1; dx <= 1; dx++) {
        int xx = x + dx;
        if (xx < 0 || xx >= Ww) continue;
        lm = fmaxf(lm, flat[yy * Ww + xx]);
      }
    }
    pk[i] = (s >= lm && s > 0.05f) ? s : 0.0f;
  }
  __syncthreads();
#pragma unroll
  for (int i = 0; i < NPIX / 256; i++) {
    int p = tid + i * 256;
    flat[p] = pk[i];
    if (pk[i] > 0.f) {
      int slot = atomicAdd(&cnt, 1);
      if (slot < CAPc) {
        cval[slot] = pk[i];
        cidx[slot] = p;
      }
    }
  }
  __syncthreads();
  const int C = cnt;
  if (C <= CAPc) {
    for (int k = 0; k < TOPKn; k++) {
      float bv = -INFINITY;
      int bi = 0x7fffffff, bs = -1;
      for (int j = tid; j < C; j += 256) {
        float v = cval[j];
        int pi = cidx[j];
        if (v > bv || (v == bv && pi < bi)) {
          bv = v;
          bi = pi;
          bs = j;
        }
      }
      for (int off = 32; off > 0; off >>= 1) {
        float ov = __shfl_xor(bv, off);
        int oi = __shfl_xor(bi, off);
        int os = __shfl_xor(bs, off);
        if (ov > bv || (ov == bv && oi < bi)) {
          bv = ov;
          bi = oi;
          bs = os;
        }
      }
      if (lane == 0) {
        rv[wid] = bv;
        ri[wid] = bi;
        rs[wid] = bs;
      }
      __syncthreads();
      if (tid == 0) {
        float Bv = rv[0];
        int Bi = ri[0], Bs = rs[0];
        for (int w = 1; w < 4; w++) {
          if (rv[w] > Bv || (rv[w] == Bv && ri[w] < Bi)) {
            Bv = rv[w];
            Bi = ri[w];
            Bs = rs[w];
          }
        }
        if (Bv > 0.f) {
          vals[b * TOPKn + k] = Bv;
          idxs[b * TOPKn + k] = Bi;
          anchor[b * NPIX + Bi] = Bv;
          cval[Bs] = -INFINITY;  // consume
        } else {
          vals[b * TOPKn + k] = 0.f;
          idxs[b * TOPKn + k] = 0;  // idx irrelevant when val==0
        }
      }
      __syncthreads();
    }
  } else {
    for (int k = 0; k < TOPKn; k++) {
      float bv = -INFINITY;
      int bi = 0x7fffffff;
      for (int p = tid; p < NPIX; p += 256) {
        float v = flat[p];
        if (v > bv || (v == bv && p < bi)) {
          bv = v;
          bi = p;
        }
      }
      for (int off = 32; off > 0; off >>= 1) {
        float ov = __shfl_xor(bv, off);
        int oi = __shfl_xor(bi, off);
        if (ov > bv || (ov == bv && oi < bi)) {
          bv = ov;
          bi = oi;
        }
      }
      if (lane == 0) {
        rv[wid] = bv;
        ri[wid] = bi;
      }
      __syncthreads();
      if (tid == 0) {
        float Bv = rv[0];
        int Bi = ri[0];
        for (int w = 1; w < 4; w++) {
          if (rv[w] > Bv || (rv[w] == Bv && ri[w] < Bi)) {
            Bv = rv[w];
            Bi = ri[w];
          }
        }
        if (Bv > 0.f) {
          vals[b * TOPKn + k] = Bv;
          idxs[b * TOPKn + k] = Bi;
          anchor[b * NPIX + Bi] = Bv;
          flat[Bi] = -INFINITY;
        } else {
          vals[b * TOPKn + k] = 0.f;
          idxs[b * TOPKn + k] = 0;
        }
      }
      __syncthreads();
    }
  }
}

// ---------------------------------------------------------------------------
// K6: per-anchor prototype argmax + oriented Gaussian stamp (atomicAdd).
// ---------------------------------------------------------------------------
__global__ __launch_bounds__(192) void k_stamp(
    const float* __restrict__ proj, const float* __restrict__ proto,
    const float* __restrict__ vals, const int* __restrict__ idxs,
    float* __restrict__ canvas) {
  int b = blockIdx.x / TOPKn, k = blockIdx.x % TOPKn;
  __shared__ float embs[12];
  __shared__ float prm[5];  // cos, sin, len, wid, val
  __shared__ int ppos[2];   // ys, xs
  if (threadIdx.x == 0) {
    int id = idxs[b * TOPKn + k];
    float v = vals[b * TOPKn + k];
    float ft[12];
    for (int r = 0; r < 12; r++)
      ft[r] = proj[(size_t)(b * Rr + r) * NPIX + id];
    float bestL = -INFINITY;
    int bp = 0;
    for (int p = 0; p < Pp; p++) {
      float L = 0.f;
      for (int r = 0; r < 12; r++) L = fmaf(ft[r], proto[p * Rr + r], L);
      if (L > bestL) {
        bestL = L;
        bp = p;
      }
    }
    const float lenL[4] = {0.4f, 0.7f, 1.0f, 1.25f};
    const float widL[4] = {0.12f, 0.18f, 0.24f, 0.3f};
    float ori = (float)((M_PI / 16.0) * (double)bp);
    prm[0] = cosf(ori);
    prm[1] = sinf(ori);
    prm[2] = lenL[bp & 3];
    prm[3] = widL[(bp >> 2) & 3];
    prm[4] = v;
    ppos[0] = id / Ww;
    ppos[1] = id % Ww;
    for (int r = 0; r < 12; r++) embs[r] = proto[bp * Rr + r];
  }
  __syncthreads();
  float v = prm[4];
  if (v <= 0.f) return;
  int t = threadIdx.x;
  if (t >= KSn * KSn) return;
  int i = t / KSn, j = t % KSn;
  float gx = (float)(-1.0 + (double)j * (1.0 / 6.0));
  float gy = (float)(-1.0 + (double)i * (1.0 / 6.0));
  float c = prm[0], s = prm[1];
  float xr = c * gx + s * gy;
  float yr = -s * gx + c * gy;
  float tx = xr / prm[2], ty = yr / prm[3];
  float foot = expf(-(tx * tx) - (ty * ty)) * v;
  int yy = ppos[0] + i - KSn / 2;
  int xx = ppos[1] + j - KSn / 2;
  if (yy < 0 || yy >= Hh || xx < 0 || xx >= Ww) return;
  float* cp = canvas + (size_t)b * Rr * NPIX + yy * Ww + xx;
#pragma unroll
  for (int r = 0; r < 12; r++) atomicAdd(cp + (size_t)r * NPIX, embs[r] * foot);
}

// ---------------------------------------------------------------------------
// K7: 1x1 conv 16->12 + GELU -> h.  in16 = [canvas*sup, occ, sup, anchor, ds]
// ---------------------------------------------------------------------------
__global__ __launch_bounds__(256) void k_post1(
    const float* __restrict__ canvas, const float* __restrict__ sup,
    const float* __restrict__ occ, const float* __restrict__ anchor,
    const float* __restrict__ ds, const float* __restrict__ w3,
    const float* __restrict__ b3, float* __restrict__ h) {
  __shared__ float w3s[12 * 16], b3s[12];
  for (int i = threadIdx.x; i < 192; i += 256) w3s[i] = w3[i];
  if (threadIdx.x < 12) b3s[threadIdx.x] = b3[threadIdx.x];
  __syncthreads();
  int pix = blockIdx.x * 256 + threadIdx.x;
  int b = pix / NPIX, hw = pix % NPIX;
  float in16[16];
  float sv = sup[pix];
#pragma unroll
  for (int r = 0; r < 12; r++)
    in16[r] = canvas[(size_t)(b * Rr + r) * NPIX + hw] * sv;
  in16[12] = occ[pix];
  in16[13] = sv;
  in16[14] = anchor[pix];
  in16[15] = ds[pix];
  float* hb = h + (size_t)b * Rr * NPIX + hw;
#pragma unroll
  for (int ro = 0; ro < 12; ro++) {
    float acc = 0.f;
#pragma unroll
    for (int ci = 0; ci < 16; ci++)
      acc = fmaf(in16[ci], w3s[ro * 16 + ci], acc);
    hb[(size_t)ro * NPIX] = gelu_f(acc + b3s[ro]);
  }
}

// ---------------------------------------------------------------------------
// K8: 1x1 conv 12->768 -> out. 4 px/thread, float4 loads+stores.
// block = (b, ocgroup of 16, hw chunk of 1024). grid = 8*48*9 = 3456.
// ---------------------------------------------------------------------------
__global__ __launch_bounds__(256) void k_post2(
    const float* __restrict__ h, const float* __restrict__ w4,
    const float* __restrict__ b4, float* __restrict__ out) {
  __shared__ float w4s[16 * 12], b4s[16];
  int bx = blockIdx.x;
  int hwblk = bx % 9;
  int g = (bx / 9) % 48;
  int b = bx / (9 * 48);
  int oc0 = g * 16;
  for (int i = threadIdx.x; i < 192; i += 256) w4s[i] = w4[oc0 * 12 + i];
  if (threadIdx.x < 16) b4s[threadIdx.x] = b4[oc0 + threadIdx.x];
  __syncthreads();
  int hw = hwblk * 1024 + threadIdx.x * 4;
  const float* hb = h + (size_t)b * Rr * NPIX + hw;
  float4 hreg[12];
#pragma unroll
  for (int r = 0; r < 12; r++)
    hreg[r] = *(const float4*)(hb + (size_t)r * NPIX);
  float* ob = out + (size_t)(b * FCn + oc0) * NPIX + hw;
#pragma unroll
  for (int j = 0; j < 16; j++) {
    float ax = 0.f, ay = 0.f, az = 0.f, aw = 0.f;
#pragma unroll
    for (int r = 0; r < 12; r++) {
      float w = w4s[j * 12 + r];
      ax = fmaf(hreg[r].x, w, ax);
      ay = fmaf(hreg[r].y, w, ay);
      az = fmaf(hreg[r].z, w, az);
      aw = fmaf(hreg[r].w, w, aw);
    }
    float bb = b4s[j];
    *(float4*)(ob + (size_t)j * NPIX) =
        make_float4(ax + bb, ay + bb, az + bb, aw + bb);
  }
}

// ---------------------------------------------------------------------------
extern "C" void kernel_launch(void* const* d_in, const int* in_sizes, int n_in,
                              void* d_out, int out_size, void* d_ws,
                              size_t ws_size, hipStream_t stream) {
  const float* features = (const float*)d_in[0];
  const float* carrier = (const float*)d_in[1];
  const float* density = (const float*)d_in[2];
  const float* w1 = (const float*)d_in[3];
  const float* b1 = (const float*)d_in[4];
  const float* w2 = (const float*)d_in[5];
  const float* b2 = (const float*)d_in[6];
  const float* w3 = (const float*)d_in[7];
  const float* b3 = (const float*)d_in[8];
  const float* w4 = (const float*)d_in[9];
  const float* b4 = (const float*)d_in[10];
  const float* proto = (const float*)d_in[11];
  float* out = (float*)d_out;
  float* ws = (float*)d_ws;

  // Workspace layout identical to the last PASSING run (~19.8 MB):
  const size_t NT = (size_t)Bn * Rr * NPIX;  // 884736
  float* t1 = ws;                            // [NT]
  float* partial = ws + NT;                  // [4*NT] (dead after k_bias_gelu)
  float* proj = partial;                     // reuse partial0
  float* canvas = partial + NT;              // reuse partial1 (zeroed in k_conv2)
  float* h = partial + 2 * NT;               // reuse partial2
  float* sm = ws + 5 * NT;
  float* occ_raw = sm;                       // [8*NPIX] x 7 maps
  float* cs_raw = sm + (size_t)Bn * NPIX;
  float* occ = sm + 2 * (size_t)Bn * NPIX;
  float* ds = sm + 3 * (size_t)Bn * NPIX;
  float* sup = sm + 4 * (size_t)Bn * NPIX;
  float* scores = sm + 5 * (size_t)Bn * NPIX;
  float* anchor = sm + 6 * (size_t)Bn * NPIX;
  float* stats = sm + 7 * (size_t)Bn * NPIX;  // 48 floats (uint-bit min/max)
  unsigned int* statsu = (unsigned int*)stats;
  float* vals = stats + 64;                   // 192 floats
  int* idxs = (int*)(vals + Bn * TOPKn);      // 192 ints

  // 1) 1x1 conv (channel-split partials), float2 px-pairs
  k_conv1_part<<<144 * 4, 256, 0, stream>>>(features, w1, partial);
  // 2) combine + bias + gelu -> t1 ; init stats
  k_bias_gelu<<<(int)(NT / 4 / 256), 256, 0, stream>>>(partial, b1, t1, statsu);
  // 3) 3x3 conv + gelu -> proj ; occ_raw ; cs_raw ; min/max ; zero canvas+anchor
  k_conv2<<<288, 256, 0, stream>>>(t1, w2, b2, carrier, density, proj, occ_raw,
                                   cs_raw, statsu, canvas, anchor);
  // 4) support mask morphology + occ/ds/scores
  k_support<<<Bn, 1024, 0, stream>>>(occ_raw, cs_raw, density, stats, occ, ds,
                                     sup, scores);
  // 5) NMS + top-24 + anchor map (candidate-compacted)
  k_topk<<<Bn, 256, 0, stream>>>(scores, vals, idxs, anchor);
  // 6) prototype select + Gaussian stamp
  k_stamp<<<Bn * TOPKn, 192, 0, stream>>>(proj, proto, vals, idxs, canvas);
  // 7) 16->12 conv + gelu
  k_post1<<<288, 256, 0, stream>>>(canvas, sup, occ, anchor, ds, w3, b3, h);
  // 8) 12->768 conv -> out (float4)
  k_post2<<<Bn * 48 * 9, 256, 0, stream>>>(h, w4, b4, out);
}